// Round 9
// baseline (120.027 us; speedup 1.0000x reference)
//
#include <hip/hip_runtime.h>
#include <math.h>

// Problem constants (match reference setup_inputs)
#define TT 4096
#define DD 512
#define EE 64
#define HH 4
#define G1 256      // D/2
#define TP 16       // positions per block (GEMM kernel)
#define NWAVE 4

typedef short  s16x8 __attribute__((ext_vector_type(8)));
typedef short  s16x4 __attribute__((ext_vector_type(4)));
typedef float  f32x4 __attribute__((ext_vector_type(4)));

__device__ __forceinline__ unsigned short f2bf(float f) {
    union { float f; unsigned u; } v; v.f = f;
    unsigned r = v.u + 0x7FFFu + ((v.u >> 16) & 1u);   // RNE
    return (unsigned short)(r >> 16);
}
__device__ __forceinline__ float bf2f(unsigned short b) {
    union { unsigned u; float f; } v; v.u = ((unsigned)b) << 16;
    return v.f;
}

// ws layout (elements of unsigned short):
//   [0, 32768)           W_hid bf16 [512][64]
//   [32768, 163840)      W_g1  bf16 [256][512]
//   [163840, ...)        seq_mem bf16 [B*T][64]  (4 MiB)
#define WS_WHID 0
#define WS_WG1  (DD * EE)
#define WS_MEM  (DD * EE + G1 * DD)

// ---- pre-pass: convert W_hid and W_g1 to bf16 in ws
__global__ __launch_bounds__(256) void convert_weights(
    const float* __restrict__ W_hid, const float* __restrict__ W_g1,
    unsigned short* __restrict__ ws) {
    int i = blockIdx.x * 256 + threadIdx.x;
    if (i < DD * EE)  ws[WS_WHID + i] = f2bf(W_hid[i]);
    if (i < G1 * DD)  ws[WS_WG1 + i] = f2bf(W_g1[i]);
}

// ---- gather kernel: one thread = one (position, 16B-slice). No LDS, low VGPR.
//      ROUND 9: launched TWICE to measure its cost: G = total - 109.8us.
__global__ __launch_bounds__(256, 8) void engram_gather(
    const int*   __restrict__ tok,     // [B,T]
    const float* __restrict__ emb,     // [H,HR,E]
    const int*   __restrict__ seeds,   // [H]
    const int*   __restrict__ p_hr,
    const int*   __restrict__ p_mn,
    unsigned short* __restrict__ ws)   // seq_mem at WS_MEM
{
    const int gt  = blockIdx.x * 256 + threadIdx.x;   // (pos, q)
    const int pos = gt >> 4;
    const int q   = gt & 15;          // covers e = q*4 .. q*4+3
    const int b   = pos >> 12;        // pos / TT
    const int t   = pos & (TT - 1);
    const int HR  = *p_hr;
    int NN = *p_mn - 1;
    if (NN > 3) NN = 3;
    if (NN < 0) NN = 0;

    const int* trow = tok + b * TT;
    const float tf0 = (float)trow[t];
    float acc[4] = {0.f, 0.f, 0.f, 0.f};
    #pragma unroll
    for (int h = 0; h < HH; ++h) {
        const float sd = (float)(seeds[h] + 1);
        float w = tf0 * sd;                            // scaled[t]
        for (int j = 0; j < NN; ++j) {
            const int n = j + 2;
            if (t <= TT - n) {
                w = w + (float)trow[t + n - 1] * sd;   // ((s0+s1)+s2) ordering
                const int idx = ((int)w) % HR;         // bit-exact vs reference
                const float4 f = *(const float4*)(emb + ((size_t)h * 262144u + (size_t)idx) * EE + q * 4);
                acc[0] += f.x; acc[1] += f.y; acc[2] += f.z; acc[3] += f.w;
            }
        }
    }
    s16x4 pk;
    #pragma unroll
    for (int k = 0; k < 4; ++k) pk[k] = (short)f2bf(acc[k] * 0.25f);
    *(s16x4*)((unsigned char*)(ws + WS_MEM) + (size_t)pos * 128 + q * 8) = pk;
}

// ---- GEMM kernel: round-4 structure, P1/P2 replaced by direct seq_mem loads.
__global__ __launch_bounds__(256, 4) void engram_mfma(
    const float* __restrict__ hidden,  // [B,T,D]
    const float* __restrict__ b_hid,   // [D]
    const float* __restrict__ b_g1,    // [G1]
    const float* __restrict__ W_g2,    // [1,G1]
    const float* __restrict__ b_g2,    // [1]
    const unsigned short* __restrict__ ws_bf,
    float*       __restrict__ out)     // [B,T,D]
{
    __shared__ __align__(16) unsigned char sGb[TP * 1024];    // g    bf16 [16][512], swizzled
    __shared__ __align__(16) unsigned char sPb[TP * 1024];    // proj bf16 [16][512], swizzled
    __shared__ float sGpart[NWAVE][TP];
    __shared__ float sGate[TP];

    const int tid  = threadIdx.x;
    const int lane = tid & 63;
    const int wave = tid >> 6;
    const int lr   = lane & 15;   // operand row / C col (position)
    const int lg   = lane >> 4;   // k-group / C row-quad
    const int pg0  = blockIdx.x * TP;

    const unsigned short* ws_whid = ws_bf + WS_WHID;   // [512][64]
    const unsigned short* ws_wg1  = ws_bf + WS_WG1;    // [256][512]
    const unsigned char*  ws_mem  = (const unsigned char*)(ws_bf + WS_MEM);

    // ---- P3: projT[d][p]; store g = h+proj+b (bf16) AND proj+b (bf16) to LDS
    {
        s16x8 bfrag[2];
        #pragma unroll
        for (int ks = 0; ks < 2; ++ks)
            bfrag[ks] = *(const s16x8*)(ws_mem + (size_t)(pg0 + lr) * 128 + ks * 64 + lg * 16);
        #pragma unroll 2
        for (int m = 0; m < 8; ++m) {
            const int Mt = wave * 8 + m;
            const int drow = Mt * 16 + lr;
            s16x8 afrag[2];
            #pragma unroll
            for (int ks = 0; ks < 2; ++ks)
                afrag[ks] = *(const s16x8*)(ws_whid + drow * EE + ks * 32 + lg * 8);
            f32x4 c = {0.f, 0.f, 0.f, 0.f};
            c = __builtin_amdgcn_mfma_f32_16x16x32_bf16(afrag[0], bfrag[0], c, 0, 0, 0);
            c = __builtin_amdgcn_mfma_f32_16x16x32_bf16(afrag[1], bfrag[1], c, 0, 0, 0);
            // lane holds C[d = Mt*16+lg*4+r][p = lr]
            const int p_c = lr;
            const int d0  = Mt * 16 + lg * 4;
            const float4 hv = *(const float4*)&hidden[(size_t)(pg0 + p_c) * DD + d0];
            const float4 bh = *(const float4*)&b_hid[d0];
            const float pr0 = c[0] + bh.x, pr1 = c[1] + bh.y;
            const float pr2 = c[2] + bh.z, pr3 = c[3] + bh.w;
            s16x4 gp, pp;
            gp[0] = (short)f2bf(hv.x + pr0);  pp[0] = (short)f2bf(pr0);
            gp[1] = (short)f2bf(hv.y + pr1);  pp[1] = (short)f2bf(pr1);
            gp[2] = (short)f2bf(hv.z + pr2);  pp[2] = (short)f2bf(pr2);
            gp[3] = (short)f2bf(hv.w + pr3);  pp[3] = (short)f2bf(pr3);
            const int cb = (d0 * 2) ^ ((p_c & 7) << 4);
            *(s16x4*)(sGb + p_c * 1024 + cb) = gp;
            *(s16x4*)(sPb + p_c * 1024 + cb) = pp;
        }
    }
    __syncthreads();

    // ---- P4: g1T[h][p] GEMM over K=512, consume into gate partials
    {
        float pgate = 0.f;
        f32x4 c[4];
        #pragma unroll
        for (int m = 0; m < 4; ++m) c[m] = (f32x4){0.f, 0.f, 0.f, 0.f};
        const int p = lr;
        #pragma unroll 4
        for (int ks = 0; ks < 16; ++ks) {
            const int ccol = ks * 64 + lg * 16;
            const s16x8 gb = *(const s16x8*)(sGb + p * 1024 + (ccol ^ ((p & 7) << 4)));
            #pragma unroll
            for (int m = 0; m < 4; ++m) {
                const int h0row = (wave * 4 + m) * 16 + lr;
                const s16x8 a = *(const s16x8*)(ws_wg1 + (size_t)h0row * DD + ks * 32 + lg * 8);
                c[m] = __builtin_amdgcn_mfma_f32_16x16x32_bf16(a, gb, c[m], 0, 0, 0);
            }
        }
        #pragma unroll
        for (int m = 0; m < 4; ++m) {
            // lane holds C[h = (wave*4+m)*16+lg*4+r][p = lr]
            const int h0 = (wave * 4 + m) * 16 + lg * 4;
            const float4 bg = *(const float4*)&b_g1[h0];
            const float4 w2 = *(const float4*)&W_g2[h0];
            #pragma unroll
            for (int r = 0; r < 4; ++r) {
                const float x = c[m][r] + ((const float*)&bg)[r];
                const float gl = 0.5f * x * (1.0f + erff(x * 0.70710678118654752f));
                pgate += gl * ((const float*)&w2)[r];
            }
        }
        pgate += __shfl_xor(pgate, 16);
        pgate += __shfl_xor(pgate, 32);
        if (lane < 16) sGpart[wave][lane] = pgate;
    }
    __syncthreads();
    if (tid < TP) {
        const float s = sGpart[0][tid] + sGpart[1][tid] + sGpart[2][tid] + sGpart[3][tid] + b_g2[0];
        sGate[tid] = 1.0f / (1.0f + expf(-s));
    }
    __syncthreads();

    // ---- P6: out = g - (1-gate)*proj  (no global reads), NT float4 stores
    {
        #pragma unroll
        for (int c4 = 0; c4 < 8; ++c4) {
            const int fidx = c4 * 256 + tid;          // float4 index in [0, 2048)
            const int p    = fidx >> 7;               // 128 float4 per position
            const int d    = (fidx & 127) * 4;
            const float cg = 1.0f - sGate[p];
            const size_t row = (size_t)(pg0 + p) * DD;
            const int cb = (d * 2) ^ ((p & 7) << 4);
            const s16x4 gv = *(const s16x4*)(sGb + p * 1024 + cb);
            const s16x4 pv = *(const s16x4*)(sPb + p * 1024 + cb);
            f32x4 o;
            o[0] = bf2f((unsigned short)gv[0]) - cg * bf2f((unsigned short)pv[0]);
            o[1] = bf2f((unsigned short)gv[1]) - cg * bf2f((unsigned short)pv[1]);
            o[2] = bf2f((unsigned short)gv[2]) - cg * bf2f((unsigned short)pv[2]);
            o[3] = bf2f((unsigned short)gv[3]) - cg * bf2f((unsigned short)pv[3]);
            __builtin_nontemporal_store(o, (f32x4*)&out[row + d]);
        }
    }
}

extern "C" void kernel_launch(void* const* d_in, const int* in_sizes, int n_in,
                              void* d_out, int out_size, void* d_ws, size_t ws_size,
                              hipStream_t stream) {
    const int*   tok    = (const int*)  d_in[0];
    const float* hidden = (const float*)d_in[1];
    const float* emb    = (const float*)d_in[2];
    const float* W_hid  = (const float*)d_in[3];
    const float* b_hid  = (const float*)d_in[4];
    const float* W_g1   = (const float*)d_in[5];
    const float* b_g1   = (const float*)d_in[6];
    const float* W_g2   = (const float*)d_in[7];
    const float* b_g2   = (const float*)d_in[8];
    const int*   seeds  = (const int*)  d_in[9];
    const int*   p_hr   = (const int*)  d_in[10];
    const int*   p_mn   = (const int*)  d_in[11];
    float* out = (float*)d_out;
    unsigned short* ws_bf = (unsigned short*)d_ws;

    const int npos = in_sizes[1] / DD;   // B*T

    convert_weights<<<dim3((G1 * DD + 255) / 256), dim3(256), 0, stream>>>(W_hid, W_g1, ws_bf);
    // MEASUREMENT ROUND: gather launched TWICE (idempotent).
    //   G = total_dur - 109.8us (round-6 total for convert+G+M).
    engram_gather<<<dim3(npos * 16 / 256), dim3(256), 0, stream>>>(
        tok, emb, seeds, p_hr, p_mn, ws_bf);
    engram_gather<<<dim3(npos * 16 / 256), dim3(256), 0, stream>>>(
        tok, emb, seeds, p_hr, p_mn, ws_bf);
    engram_mfma<<<dim3(npos / TP), dim3(256), 0, stream>>>(
        hidden, b_hid, b_g1, W_g2, b_g2, ws_bf, out);
}

// Round 10
// 100.449 us; speedup vs baseline: 1.1949x; 1.1949x over previous
//
#include <hip/hip_runtime.h>
#include <math.h>

// Problem constants (match reference setup_inputs)
#define TT 4096
#define DD 512
#define EE 64
#define HH 4
#define G1 256      // D/2
#define TP 16       // positions per block
#define NWAVE 4

typedef short  s16x8 __attribute__((ext_vector_type(8)));
typedef short  s16x4 __attribute__((ext_vector_type(4)));
typedef float  f32x4 __attribute__((ext_vector_type(4)));

__device__ __forceinline__ unsigned short f2bf(float f) {
    union { float f; unsigned u; } v; v.f = f;
    unsigned r = v.u + 0x7FFFu + ((v.u >> 16) & 1u);   // RNE
    return (unsigned short)(r >> 16);
}
__device__ __forceinline__ float bf2f(unsigned short b) {
    union { unsigned u; float f; } v; v.u = ((unsigned)b) << 16;
    return v.f;
}

// ---- pre-pass: convert W_hid [512][64] and W_g1 [256][512] to bf16 in ws
__global__ __launch_bounds__(256) void convert_weights(
    const float* __restrict__ W_hid, const float* __restrict__ W_g1,
    unsigned short* __restrict__ ws) {
    int i = blockIdx.x * 256 + threadIdx.x;
    if (i < DD * EE)  ws[i] = f2bf(W_hid[i]);
    if (i < G1 * DD)  ws[DD * EE + i] = f2bf(W_g1[i]);
}

__global__ __launch_bounds__(256, 4) void engram_mfma(
    const int*   __restrict__ tok,     // [B,T]
    const float* __restrict__ hidden,  // [B,T,D]
    const float* __restrict__ emb,     // [H,HR,E]
    const float* __restrict__ b_hid,   // [D]
    const float* __restrict__ b_g1,    // [G1]
    const float* __restrict__ W_g2,    // [1,G1]
    const float* __restrict__ b_g2,    // [1]
    const int*   __restrict__ seeds,   // [H]
    const int*   __restrict__ p_hr,
    const int*   __restrict__ p_mn,
    const unsigned short* __restrict__ ws_bf,  // W_hid bf16 | W_g1 bf16
    float*       __restrict__ out)     // [B,T,D]
{
    __shared__ __align__(16) unsigned char sMemb[TP * 128];   // seq_mem bf16 [16][64], swizzled
    __shared__ __align__(16) unsigned char sGb[TP * 1024];    // g    bf16 [16][512], swizzled
    __shared__ __align__(16) unsigned char sPb[TP * 1024];    // proj bf16 [16][512], swizzled
    __shared__ float sGpart[NWAVE][TP];
    __shared__ float sGate[TP];

    const int tid  = threadIdx.x;
    const int lane = tid & 63;
    const int wave = tid >> 6;
    const int lr   = lane & 15;   // operand row / C col (position)
    const int lg   = lane >> 4;   // k-group / C row-quad
    const int pg0  = blockIdx.x * TP;
    const int b    = pg0 / TT;
    const int t0   = pg0 % TT;
    const int HR   = *p_hr;
    int NN = *p_mn - 1;
    if (NN > 3) NN = 3;
    if (NN < 0) NN = 0;

    const unsigned short* ws_whid = ws_bf;             // [512][64]
    const unsigned short* ws_wg1  = ws_bf + DD * EE;   // [256][512]

    // ---- P1+P2 fused: per-thread hash (bit-exact fp32 replication) + gather
    {
        const int p = tid >> 4, q = tid & 15;   // q covers e = q*4 .. q*4+3
        const int t = t0 + p;
        const int* trow = tok + b * TT;
        const float tf0 = (float)trow[t];
        float acc[4] = {0.f, 0.f, 0.f, 0.f};
        #pragma unroll
        for (int h = 0; h < HH; ++h) {
            const float sd = (float)(seeds[h] + 1);
            float w = tf0 * sd;
            for (int j = 0; j < NN; ++j) {
                const int n = j + 2;
                if (t <= TT - n) {
                    w = w + (float)trow[t + n - 1] * sd;   // ((s0+s1)+s2) ordering
                    const int idx = ((int)w) % HR;
                    const float4 f = *(const float4*)(emb + ((size_t)h * 262144u + (size_t)idx) * EE + q * 4);
                    acc[0] += f.x; acc[1] += f.y; acc[2] += f.z; acc[3] += f.w;
                }
            }
        }
        s16x4 pk;
        #pragma unroll
        for (int k = 0; k < 4; ++k) pk[k] = (short)f2bf(acc[k] * 0.25f);
        const int c = q * 8;   // byte col
        *(s16x4*)(sMemb + p * 128 + (c ^ ((p & 7) << 4))) = pk;
    }
    __syncthreads();

    // ---- P3: projT[d][p] via MFMA; write proj+b (bf16, swizzled) ONLY.
    //      Hidden is NOT touched here (its fragment-layout read was 16 lines
    //      per wave instruction -> the kernel's real bottleneck).
    {
        s16x8 bfrag[2];
        #pragma unroll
        for (int ks = 0; ks < 2; ++ks) {
            const int p = lr;
            const int c = ks * 64 + lg * 16;
            bfrag[ks] = *(const s16x8*)(sMemb + p * 128 + (c ^ ((p & 7) << 4)));
        }
        #pragma unroll 2
        for (int m = 0; m < 8; ++m) {
            const int Mt = wave * 8 + m;
            const int drow = Mt * 16 + lr;
            s16x8 afrag[2];
            #pragma unroll
            for (int ks = 0; ks < 2; ++ks)
                afrag[ks] = *(const s16x8*)(ws_whid + drow * EE + ks * 32 + lg * 8);
            f32x4 c = {0.f, 0.f, 0.f, 0.f};
            c = __builtin_amdgcn_mfma_f32_16x16x32_bf16(afrag[0], bfrag[0], c, 0, 0, 0);
            c = __builtin_amdgcn_mfma_f32_16x16x32_bf16(afrag[1], bfrag[1], c, 0, 0, 0);
            // lane holds C[d = Mt*16+lg*4+r][p = lr]
            const int p_c = lr;
            const int d0  = Mt * 16 + lg * 4;
            const float4 bh = *(const float4*)&b_hid[d0];
            s16x4 pp;
            pp[0] = (short)f2bf(c[0] + bh.x);
            pp[1] = (short)f2bf(c[1] + bh.y);
            pp[2] = (short)f2bf(c[2] + bh.z);
            pp[3] = (short)f2bf(c[3] + bh.w);
            *(s16x4*)(sPb + p_c * 1024 + ((d0 * 2) ^ ((p_c & 7) << 4))) = pp;
        }
    }
    __syncthreads();

    // ---- P3.5: lane-contiguous hidden pass: g = h + proj -> sGb (bf16).
    //      8 back-to-back float4 loads (1KB/wave-instr, 8-deep MLP).
    {
        f32x4 hreg[8];
        #pragma unroll
        for (int c4 = 0; c4 < 8; ++c4) {
            const int fidx = c4 * 256 + tid;          // float4 index in [0, 2048)
            hreg[c4] = *(const f32x4*)&hidden[(size_t)(pg0 + (fidx >> 7)) * DD + (fidx & 127) * 4];
        }
        #pragma unroll
        for (int c4 = 0; c4 < 8; ++c4) {
            const int fidx = c4 * 256 + tid;
            const int p    = fidx >> 7;
            const int d    = (fidx & 127) * 4;
            const int cb   = (d * 2) ^ ((p & 7) << 4);
            const s16x4 pv = *(const s16x4*)(sPb + p * 1024 + cb);
            s16x4 gp;
            gp[0] = (short)f2bf(hreg[c4][0] + bf2f((unsigned short)pv[0]));
            gp[1] = (short)f2bf(hreg[c4][1] + bf2f((unsigned short)pv[1]));
            gp[2] = (short)f2bf(hreg[c4][2] + bf2f((unsigned short)pv[2]));
            gp[3] = (short)f2bf(hreg[c4][3] + bf2f((unsigned short)pv[3]));
            *(s16x4*)(sGb + p * 1024 + cb) = gp;
        }
    }
    __syncthreads();

    // ---- P4: g1T[h][p] GEMM over K=512, consume into gate partials
    {
        float pgate = 0.f;
        f32x4 c[4];
        #pragma unroll
        for (int m = 0; m < 4; ++m) c[m] = (f32x4){0.f, 0.f, 0.f, 0.f};
        const int p = lr;
        #pragma unroll 4
        for (int ks = 0; ks < 16; ++ks) {
            const int ccol = ks * 64 + lg * 16;
            const s16x8 gb = *(const s16x8*)(sGb + p * 1024 + (ccol ^ ((p & 7) << 4)));
            #pragma unroll
            for (int m = 0; m < 4; ++m) {
                const int h0row = (wave * 4 + m) * 16 + lr;
                const s16x8 a = *(const s16x8*)(ws_wg1 + (size_t)h0row * DD + ks * 32 + lg * 8);
                c[m] = __builtin_amdgcn_mfma_f32_16x16x32_bf16(a, gb, c[m], 0, 0, 0);
            }
        }
        #pragma unroll
        for (int m = 0; m < 4; ++m) {
            // lane holds C[h = (wave*4+m)*16+lg*4+r][p = lr]
            const int h0 = (wave * 4 + m) * 16 + lg * 4;
            const float4 bg = *(const float4*)&b_g1[h0];
            const float4 w2 = *(const float4*)&W_g2[h0];
            #pragma unroll
            for (int r = 0; r < 4; ++r) {
                const float x = c[m][r] + ((const float*)&bg)[r];
                const float gl = 0.5f * x * (1.0f + erff(x * 0.70710678118654752f));
                pgate += gl * ((const float*)&w2)[r];
            }
        }
        pgate += __shfl_xor(pgate, 16);
        pgate += __shfl_xor(pgate, 32);
        if (lane < 16) sGpart[wave][lane] = pgate;
    }
    __syncthreads();
    if (tid < TP) {
        const float s = sGpart[0][tid] + sGpart[1][tid] + sGpart[2][tid] + sGpart[3][tid] + b_g2[0];
        sGate[tid] = 1.0f / (1.0f + expf(-s));
    }
    __syncthreads();

    // ---- P6: out = g - (1-gate)*proj  (no global reads), NT float4 stores
    {
        #pragma unroll
        for (int c4 = 0; c4 < 8; ++c4) {
            const int fidx = c4 * 256 + tid;          // float4 index in [0, 2048)
            const int p    = fidx >> 7;               // 128 float4 per position
            const int d    = (fidx & 127) * 4;
            const float cg = 1.0f - sGate[p];
            const size_t row = (size_t)(pg0 + p) * DD;
            const int cb = (d * 2) ^ ((p & 7) << 4);
            const s16x4 gv = *(const s16x4*)(sGb + p * 1024 + cb);
            const s16x4 pv = *(const s16x4*)(sPb + p * 1024 + cb);
            f32x4 o;
            o[0] = bf2f((unsigned short)gv[0]) - cg * bf2f((unsigned short)pv[0]);
            o[1] = bf2f((unsigned short)gv[1]) - cg * bf2f((unsigned short)pv[1]);
            o[2] = bf2f((unsigned short)gv[2]) - cg * bf2f((unsigned short)pv[2]);
            o[3] = bf2f((unsigned short)gv[3]) - cg * bf2f((unsigned short)pv[3]);
            __builtin_nontemporal_store(o, (f32x4*)&out[row + d]);
        }
    }
}

extern "C" void kernel_launch(void* const* d_in, const int* in_sizes, int n_in,
                              void* d_out, int out_size, void* d_ws, size_t ws_size,
                              hipStream_t stream) {
    const int*   tok    = (const int*)  d_in[0];
    const float* hidden = (const float*)d_in[1];
    const float* emb    = (const float*)d_in[2];
    const float* W_hid  = (const float*)d_in[3];
    const float* b_hid  = (const float*)d_in[4];
    const float* W_g1   = (const float*)d_in[5];
    const float* b_g1   = (const float*)d_in[6];
    const float* W_g2   = (const float*)d_in[7];
    const float* b_g2   = (const float*)d_in[8];
    const int*   seeds  = (const int*)  d_in[9];
    const int*   p_hr   = (const int*)  d_in[10];
    const int*   p_mn   = (const int*)  d_in[11];
    float* out = (float*)d_out;
    unsigned short* ws_bf = (unsigned short*)d_ws;

    convert_weights<<<dim3((G1 * DD + 255) / 256), dim3(256), 0, stream>>>(W_hid, W_g1, ws_bf);

    const int npos = in_sizes[1] / DD;   // B*T
    engram_mfma<<<dim3(npos / TP), dim3(256), 0, stream>>>(
        tok, hidden, emb, b_hid, b_g1, W_g2, b_g2, seeds, p_hr, p_mn, ws_bf, out);
}